// Round 1
// baseline (1872.700 us; speedup 1.0000x reference)
//
#include <hip/hip_runtime.h>
#include <math.h>

#define BB 16
#define CIN 256
#define COUT 256
#define HH 64
#define WW 64
#define NBANK_STRIDE 589824  // 256*256*9

// ws layout (floats):
// [0,4096)     pooled [16][256]
// [4096,4160)  alpha  [16][4]
// [4160,4416)  bn scale [256]
// [4416,4672)  bn shift [256]

struct AttnParams {
    const float* w1[4];
    const float* w2[4];
    const float* b2[4];
};

__global__ __launch_bounds__(256) void gap_kernel(const float* __restrict__ x,
                                                  float* __restrict__ pooled) {
    const int plane = blockIdx.x;  // b*256 + c
    const float4* p = (const float4*)(x + (size_t)plane * 4096);
    const int t = threadIdx.x;
    float s = 0.f;
#pragma unroll
    for (int i = 0; i < 4; ++i) {
        float4 v = p[t + 256 * i];
        s += v.x + v.y + v.z + v.w;
    }
#pragma unroll
    for (int off = 32; off > 0; off >>= 1) s += __shfl_down(s, off, 64);
    __shared__ float red[4];
    if ((t & 63) == 0) red[t >> 6] = s;
    __syncthreads();
    if (t == 0) pooled[plane] = (red[0] + red[1] + red[2] + red[3]) * (1.0f / 4096.0f);
}

__global__ __launch_bounds__(64) void attn_kernel(const float* __restrict__ pooled,
                                                  AttnParams p,
                                                  float* __restrict__ alpha) {
    const int b = blockIdx.x;
    const int t = threadIdx.x;
    __shared__ float ps[256];
    __shared__ float hs[64];
    __shared__ float lg[4];
    __shared__ float prod[4];
#pragma unroll
    for (int i = 0; i < 4; ++i) ps[t + 64 * i] = pooled[b * 256 + t + 64 * i];
    if (t < 4) prod[t] = 1.f;
    __syncthreads();
    for (int n = 0; n < 4; ++n) {
        const float* w1 = p.w1[n];
        float h = 0.f;
        for (int c = 0; c < 256; ++c) h += w1[t * 256 + c] * ps[c];
        hs[t] = fmaxf(h, 0.f);
        __syncthreads();
        if (t < 4) {
            const float* w2 = p.w2[n];
            float l = p.b2[n][t];
            for (int m = 0; m < 64; ++m) l += w2[t * 64 + m] * hs[m];
            lg[t] = l;
        }
        __syncthreads();
        if (t == 0) {
            float mx = fmaxf(fmaxf(lg[0], lg[1]), fmaxf(lg[2], lg[3]));
            float e0 = expf(lg[0] - mx), e1 = expf(lg[1] - mx);
            float e2 = expf(lg[2] - mx), e3 = expf(lg[3] - mx);
            float inv = 1.f / (e0 + e1 + e2 + e3);
            prod[0] *= e0 * inv;
            prod[1] *= e1 * inv;
            prod[2] *= e2 * inv;
            prod[3] *= e3 * inv;
        }
        __syncthreads();
    }
    if (t < 4) alpha[b * 4 + t] = prod[t];
}

// Tile: 64 c_out x 64 w (one output row h) per block. 256 threads,
// thread computes 4 co x 4 w. K-loop: kh(3) x ci-chunk(8 of 32) x ci(32) x kw(3).
__global__ __launch_bounds__(256) void conv_kernel(const float* __restrict__ x,
                                                   const float* __restrict__ wt,
                                                   const float* __restrict__ alpha,
                                                   float* __restrict__ out) {
    const int h = blockIdx.x;    // 0..63
    const int cot = blockIdx.y;  // 0..3
    const int b = blockIdx.z;    // 0..15
    const int t = threadIdx.x;
    const int tx = t & 15;   // co group
    const int ty = t >> 4;   // w group
    const int co0 = cot * 64;

    __shared__ __align__(16) float xs[32][68];      // [ci][1+w], halo cols 0 and 65 zero
    __shared__ __align__(16) float wsh[3][32][68];  // [kw][ci][co], co padded 64->68

    const float a0 = alpha[b * 4 + 0];
    const float a1 = alpha[b * 4 + 1];
    const float a2 = alpha[b * 4 + 2];
    const float a3 = alpha[b * 4 + 3];

    float acc[4][4];
#pragma unroll
    for (int i = 0; i < 4; ++i)
#pragma unroll
        for (int j = 0; j < 4; ++j) acc[i][j] = 0.f;

    const size_t xbase = (size_t)b * CIN * 4096;

    for (int kh = 0; kh < 3; ++kh) {
        const int r = h + kh - 1;
        if (r < 0 || r >= HH) continue;  // uniform per block
        for (int chunk = 0; chunk < 8; ++chunk) {
            const int ci0 = chunk * 32;
            __syncthreads();
            // stage x: 32 ci x 64 w, coalesced (64 lanes = one row)
#pragma unroll
            for (int i = 0; i < 8; ++i) {
                int flat = t + 256 * i;
                int ci = flat >> 6;
                int w = flat & 63;
                xs[ci][1 + w] = x[xbase + (size_t)(ci0 + ci) * 4096 + r * 64 + w];
            }
            if (t < 32) {
                xs[t][0] = 0.f;
                xs[t][65] = 0.f;
                xs[t][66] = 0.f;
                xs[t][67] = 0.f;
            }
            // stage combined dynamic weights: 64co x 32ci x 3kw
#pragma unroll
            for (int j = 0; j < 24; ++j) {
                int e = t + 256 * j;
                int co = e / 96;
                int rem = e - co * 96;
                int ci = rem / 3;
                int kw = rem - ci * 3;
                size_t g = (((size_t)(co0 + co) * 256 + (ci0 + ci)) * 3 + kh) * 3 + kw;
                float v = a0 * wt[g] + a1 * wt[g + NBANK_STRIDE] +
                          a2 * wt[g + 2 * NBANK_STRIDE] + a3 * wt[g + 3 * NBANK_STRIDE];
                wsh[kw][ci][co] = v;
            }
            __syncthreads();
            // compute
            for (int ci = 0; ci < 32; ++ci) {
                float4 w0 = *(const float4*)&wsh[0][ci][tx * 4];
                float4 w1v = *(const float4*)&wsh[1][ci][tx * 4];
                float4 w2v = *(const float4*)&wsh[2][ci][tx * 4];
                float4 xa = *(const float4*)&xs[ci][ty * 4];
                float4 xb = *(const float4*)&xs[ci][ty * 4 + 4];
                float v[8] = {xa.x, xa.y, xa.z, xa.w, xb.x, xb.y, xb.z, xb.w};
                float aw[3][4] = {{w0.x, w0.y, w0.z, w0.w},
                                  {w1v.x, w1v.y, w1v.z, w1v.w},
                                  {w2v.x, w2v.y, w2v.z, w2v.w}};
#pragma unroll
                for (int kw = 0; kw < 3; ++kw)
#pragma unroll
                    for (int i = 0; i < 4; ++i)
#pragma unroll
                        for (int j = 0; j < 4; ++j)
                            acc[i][j] += aw[kw][i] * v[j + kw];
            }
        }
    }
    // epilogue: pre-BN output
    size_t obase = (((size_t)b * COUT + co0 + tx * 4) * 64 + h) * 64 + ty * 4;
#pragma unroll
    for (int i = 0; i < 4; ++i) {
        float4 o = {acc[i][0], acc[i][1], acc[i][2], acc[i][3]};
        *(float4*)&out[obase + (size_t)i * 4096] = o;
    }
}

__global__ __launch_bounds__(256) void bn_stats_kernel(const float* __restrict__ out,
                                                       const float* __restrict__ gamma,
                                                       const float* __restrict__ beta,
                                                       float* __restrict__ scale,
                                                       float* __restrict__ shift) {
    const int co = blockIdx.x;
    const int t = threadIdx.x;
    float s = 0.f, sq = 0.f;
    for (int b = 0; b < BB; ++b) {
        const float4* p = (const float4*)(out + ((size_t)b * 256 + co) * 4096);
#pragma unroll
        for (int i = 0; i < 4; ++i) {
            float4 v = p[t + 256 * i];
            s += v.x + v.y + v.z + v.w;
            sq += v.x * v.x + v.y * v.y + v.z * v.z + v.w * v.w;
        }
    }
#pragma unroll
    for (int off = 32; off > 0; off >>= 1) {
        s += __shfl_down(s, off, 64);
        sq += __shfl_down(sq, off, 64);
    }
    __shared__ float rs[4], rq[4];
    if ((t & 63) == 0) {
        rs[t >> 6] = s;
        rq[t >> 6] = sq;
    }
    __syncthreads();
    if (t == 0) {
        float S = rs[0] + rs[1] + rs[2] + rs[3];
        float Q = rq[0] + rq[1] + rq[2] + rq[3];
        float mean = S * (1.f / 65536.f);
        float var = Q * (1.f / 65536.f) - mean * mean;
        float inv = rsqrtf(var + 1e-5f);
        float sc = gamma[co] * inv;
        scale[co] = sc;
        shift[co] = beta[co] - mean * sc;
    }
}

__global__ __launch_bounds__(256) void bn_apply_kernel(float* __restrict__ out,
                                                       const float* __restrict__ scale,
                                                       const float* __restrict__ shift) {
    const int gid = blockIdx.x * 256 + threadIdx.x;  // float4 index
    const int c = (gid >> 10) & 255;                 // 1024 float4 per (b,c) plane
    float4* p = (float4*)out;
    float4 v = p[gid];
    const float sc = scale[c], sh = shift[c];
    v.x = v.x * sc + sh;
    v.y = v.y * sc + sh;
    v.z = v.z * sc + sh;
    v.w = v.w * sc + sh;
    p[gid] = v;
}

extern "C" void kernel_launch(void* const* d_in, const int* in_sizes, int n_in,
                              void* d_out, int out_size, void* d_ws, size_t ws_size,
                              hipStream_t stream) {
    (void)in_sizes; (void)n_in; (void)out_size; (void)ws_size;
    const float* x = (const float*)d_in[0];
    const float* wt = (const float*)d_in[1];
    const float* gamma = (const float*)d_in[2];
    const float* beta = (const float*)d_in[3];
    AttnParams ap;
    for (int n = 0; n < 4; ++n) {
        ap.w1[n] = (const float*)d_in[4 + 3 * n];
        ap.w2[n] = (const float*)d_in[5 + 3 * n];
        ap.b2[n] = (const float*)d_in[6 + 3 * n];
    }
    float* ws = (float*)d_ws;
    float* pooled = ws;
    float* alpha = ws + 4096;
    float* scale = ws + 4160;
    float* shift = ws + 4416;
    float* out = (float*)d_out;

    gap_kernel<<<4096, 256, 0, stream>>>(x, pooled);
    attn_kernel<<<16, 64, 0, stream>>>(pooled, ap, alpha);
    conv_kernel<<<dim3(64, 4, 16), 256, 0, stream>>>(x, wt, alpha, out);
    bn_stats_kernel<<<256, 256, 0, stream>>>(out, gamma, beta, scale, shift);
    bn_apply_kernel<<<16384, 256, 0, stream>>>(out, scale, shift);
}

// Round 2
// 335.589 us; speedup vs baseline: 5.5803x; 5.5803x over previous
//
#include <hip/hip_runtime.h>
#include <math.h>

#define BB 16
#define CIN 256
#define COUT 256
#define HH 64
#define WW 64
#define NBANK_STRIDE 589824  // 256*256*9

typedef short bf16x8 __attribute__((ext_vector_type(8)));
typedef float f32x4 __attribute__((ext_vector_type(4)));

// ws layout (bytes):
// [0,16384)                pooled [16][256] f32
// [16384,16640)            alpha  [16][4] f32
// [16640,17664)            bn scale [256] f32
// [17664,18688)            bn shift [256] f32
// [32768, +33554432)       xT  [16][4096 pix][256 ci] bf16  (NHWC)
// [33587200, +18874368)    dynwT [16][9 khw][256 co][256 ci] bf16
#define WS_XT_OFF 32768
#define WS_DW_OFF 33587200
#define WS_NEED   52461568ULL

static __device__ __forceinline__ unsigned short f2bf(float f) {
    union { float f; unsigned u; } v; v.f = f;
    unsigned r = v.u + 0x7FFF + ((v.u >> 16) & 1);
    return (unsigned short)(r >> 16);
}

struct AttnParams {
    const float* w1[4];
    const float* w2[4];
    const float* b2[4];
};

__global__ __launch_bounds__(256) void gap_kernel(const float* __restrict__ x,
                                                  float* __restrict__ pooled) {
    const int plane = blockIdx.x;  // b*256 + c
    const float4* p = (const float4*)(x + (size_t)plane * 4096);
    const int t = threadIdx.x;
    float s = 0.f;
#pragma unroll
    for (int i = 0; i < 4; ++i) {
        float4 v = p[t + 256 * i];
        s += v.x + v.y + v.z + v.w;
    }
#pragma unroll
    for (int off = 32; off > 0; off >>= 1) s += __shfl_down(s, off, 64);
    __shared__ float red[4];
    if ((t & 63) == 0) red[t >> 6] = s;
    __syncthreads();
    if (t == 0) pooled[plane] = (red[0] + red[1] + red[2] + red[3]) * (1.0f / 4096.0f);
}

__global__ __launch_bounds__(64) void attn_kernel(const float* __restrict__ pooled,
                                                  AttnParams p,
                                                  float* __restrict__ alpha) {
    const int b = blockIdx.x;
    const int t = threadIdx.x;
    __shared__ float ps[256];
    __shared__ float hs[64];
    __shared__ float lg[4];
    __shared__ float prod[4];
#pragma unroll
    for (int i = 0; i < 4; ++i) ps[t + 64 * i] = pooled[b * 256 + t + 64 * i];
    if (t < 4) prod[t] = 1.f;
    __syncthreads();
    for (int n = 0; n < 4; ++n) {
        const float* w1 = p.w1[n];
        float h = 0.f;
        for (int c = 0; c < 256; ++c) h += w1[t * 256 + c] * ps[c];
        hs[t] = fmaxf(h, 0.f);
        __syncthreads();
        if (t < 4) {
            const float* w2 = p.w2[n];
            float l = p.b2[n][t];
            for (int m = 0; m < 64; ++m) l += w2[t * 64 + m] * hs[m];
            lg[t] = l;
        }
        __syncthreads();
        if (t == 0) {
            float mx = fmaxf(fmaxf(lg[0], lg[1]), fmaxf(lg[2], lg[3]));
            float e0 = expf(lg[0] - mx), e1 = expf(lg[1] - mx);
            float e2 = expf(lg[2] - mx), e3 = expf(lg[3] - mx);
            float inv = 1.f / (e0 + e1 + e2 + e3);
            prod[0] *= e0 * inv;
            prod[1] *= e1 * inv;
            prod[2] *= e2 * inv;
            prod[3] *= e3 * inv;
        }
        __syncthreads();
    }
    if (t < 4) alpha[b * 4 + t] = prod[t];
}

// x [b][ci][h][w] f32  ->  xT [b][h*64+w][ci] bf16 (NHWC), via LDS tile transpose.
__global__ __launch_bounds__(256) void xpose_kernel(const float* __restrict__ x,
                                                    unsigned short* __restrict__ xT) {
    const int ci0 = blockIdx.x * 32;
    const int h = blockIdx.y;
    const int b = blockIdx.z;
    const int t = threadIdx.x;
    __shared__ __align__(16) unsigned short tile[64][40];  // [w][ci]
    {
        const int ci = t >> 3;    // 0..31
        const int l = t & 7;      // 0..7
        const float4* src = (const float4*)(x + ((size_t)(b * 256 + ci0 + ci)) * 4096 + h * 64);
        float4 v1 = src[l * 2];
        float4 v2 = src[l * 2 + 1];
        tile[l * 8 + 0][ci] = f2bf(v1.x);
        tile[l * 8 + 1][ci] = f2bf(v1.y);
        tile[l * 8 + 2][ci] = f2bf(v1.z);
        tile[l * 8 + 3][ci] = f2bf(v1.w);
        tile[l * 8 + 4][ci] = f2bf(v2.x);
        tile[l * 8 + 5][ci] = f2bf(v2.y);
        tile[l * 8 + 6][ci] = f2bf(v2.z);
        tile[l * 8 + 7][ci] = f2bf(v2.w);
    }
    __syncthreads();
    {
        const int w = t >> 2;    // 0..63
        const int s = t & 3;     // 0..3
        bf16x8 val = *(const bf16x8*)&tile[w][s * 8];
        *(bf16x8*)&xT[((size_t)b * 4096 + h * 64 + w) * 256 + ci0 + s * 8] = val;
    }
}

// dynwT[b][khw][co][ci] = sum_n alpha[b][n] * wt[n][co][ci][kh][kw], bf16.
__global__ __launch_bounds__(256) void dynw_kernel(const float* __restrict__ wt,
                                                   const float* __restrict__ alpha,
                                                   unsigned short* __restrict__ dynwT) {
    const int co = blockIdx.x;
    const int ci = threadIdx.x;
    float w[4][9];
#pragma unroll
    for (int n = 0; n < 4; ++n) {
        const size_t base = ((size_t)(n * 256 + co) * 256 + ci) * 9;
#pragma unroll
        for (int k = 0; k < 9; ++k) w[n][k] = wt[base + k];
    }
    for (int b = 0; b < BB; ++b) {
        const float a0 = alpha[b * 4 + 0];
        const float a1 = alpha[b * 4 + 1];
        const float a2 = alpha[b * 4 + 2];
        const float a3 = alpha[b * 4 + 3];
#pragma unroll
        for (int k = 0; k < 9; ++k) {
            float v = a0 * w[0][k] + a1 * w[1][k] + a2 * w[2][k] + a3 * w[3][k];
            dynwT[((size_t)(b * 9 + k) * 256 + co) * 256 + ci] = f2bf(v);
        }
    }
}

// Implicit-GEMM conv via MFMA 16x16x32 bf16.
// Block: 128 co x 128 pixels (2 output rows). 4 waves, each 64x64.
// K-loop: 8 ci-chunks (32 each) x 9 (kh,kw). xs holds 4-row/66-col halo.
__global__ __launch_bounds__(256) void conv_mfma_kernel(const unsigned short* __restrict__ xT,
                                                        const unsigned short* __restrict__ dynwT,
                                                        float* __restrict__ out) {
    const int nt = blockIdx.x;    // 0..31 -> rows {2nt, 2nt+1}
    const int mt = blockIdx.y;    // 0..1  -> co0 = 128*mt
    const int b = blockIdx.z;
    const int t = threadIdx.x;
    const int lane = t & 63;
    const int wv = t >> 6;
    const int wx = wv & 1;        // pixel half (row within pair)
    const int wy = wv >> 1;       // co half
    const int mh = lane & 15;     // m-hat / n-hat within 16x16 tile
    const int q = lane >> 4;      // quad 0..3
    const int r0 = nt * 2;
    const int co0 = mt * 128;

    __shared__ __align__(16) short xs[264 * 40];   // [p=lr*66+lc][ci], pad 32->40
    __shared__ __align__(16) short As[128 * 40];   // [co][ci], pad 32->40

    f32x4 acc[4][4];
#pragma unroll
    for (int i = 0; i < 4; ++i)
#pragma unroll
        for (int j = 0; j < 4; ++j) acc[i][j] = (f32x4){0.f, 0.f, 0.f, 0.f};

    const int a_base = (wy * 64 + mh) * 40 + q * 8;       // + mi*640
    const bf16x8 zero8 = {0, 0, 0, 0, 0, 0, 0, 0};

    for (int cc = 0; cc < 8; ++cc) {
        const int ci0 = cc * 32;
        __syncthreads();
        // stage xs: 264 pixels x 32 ci (zero-padded halo)
#pragma unroll
        for (int i = 0; i < 5; ++i) {
            int idx = t + 256 * i;
            if (idx < 1056) {
                int p = idx >> 2;
                int sub = idx & 3;
                int lr = p / 66;
                int lc = p - lr * 66;
                int r = r0 - 1 + lr;
                int c = lc - 1;
                bf16x8 v = zero8;
                if ((unsigned)r < 64u && (unsigned)c < 64u)
                    v = *(const bf16x8*)&xT[((size_t)b * 4096 + r * 64 + c) * 256 + ci0 + sub * 8];
                *(bf16x8*)&xs[p * 40 + sub * 8] = v;
            }
        }
        for (int khw = 0; khw < 9; ++khw) {
            const int kh = khw / 3;
            const int kw = khw - kh * 3;
            if (khw) __syncthreads();
            // stage As: 128 co x 32 ci
#pragma unroll
            for (int i = 0; i < 2; ++i) {
                int e = t * 2 + i;
                int row = e >> 2;
                int sub = e & 3;
                bf16x8 v = *(const bf16x8*)&dynwT[((size_t)(b * 9 + khw) * 256 + co0 + row) * 256 + ci0 + sub * 8];
                *(bf16x8*)&As[row * 40 + sub * 8] = v;
            }
            __syncthreads();
            // compute: 16 mfma per wave
            const int boff = ((wx + kh) * 66 + kw + mh) * 40 + q * 8;
            bf16x8 bf[4], af[4];
#pragma unroll
            for (int ni = 0; ni < 4; ++ni) bf[ni] = *(const bf16x8*)&xs[boff + ni * 640];
#pragma unroll
            for (int mi = 0; mi < 4; ++mi) af[mi] = *(const bf16x8*)&As[a_base + mi * 640];
#pragma unroll
            for (int mi = 0; mi < 4; ++mi)
#pragma unroll
                for (int ni = 0; ni < 4; ++ni)
                    acc[mi][ni] = __builtin_amdgcn_mfma_f32_16x16x32_bf16(af[mi], bf[ni], acc[mi][ni], 0, 0, 0);
        }
    }
    // epilogue: D row = co (q*4+reg), col = pixel (mh)
    const int h = r0 + wx;
#pragma unroll
    for (int mi = 0; mi < 4; ++mi) {
#pragma unroll
        for (int ni = 0; ni < 4; ++ni) {
            const int w = ni * 16 + mh;
#pragma unroll
            for (int reg = 0; reg < 4; ++reg) {
                const int co = co0 + wy * 64 + mi * 16 + q * 4 + reg;
                out[(((size_t)b * 256 + co) << 12) + (h << 6) + w] = acc[mi][ni][reg];
            }
        }
    }
}

// ---- fp32 fallback conv (round-1 path, used only if ws_size too small) ----
__global__ __launch_bounds__(256) void conv_fp32_kernel(const float* __restrict__ x,
                                                        const float* __restrict__ wt,
                                                        const float* __restrict__ alpha,
                                                        float* __restrict__ out) {
    const int h = blockIdx.x;
    const int cot = blockIdx.y;
    const int b = blockIdx.z;
    const int t = threadIdx.x;
    const int tx = t & 15;
    const int ty = t >> 4;
    const int co0 = cot * 64;

    __shared__ __align__(16) float xsf[32][68];
    __shared__ __align__(16) float wshf[3][32][68];

    const float a0 = alpha[b * 4 + 0];
    const float a1 = alpha[b * 4 + 1];
    const float a2 = alpha[b * 4 + 2];
    const float a3 = alpha[b * 4 + 3];

    float acc[4][4];
#pragma unroll
    for (int i = 0; i < 4; ++i)
#pragma unroll
        for (int j = 0; j < 4; ++j) acc[i][j] = 0.f;

    const size_t xbase = (size_t)b * CIN * 4096;

    for (int kh = 0; kh < 3; ++kh) {
        const int r = h + kh - 1;
        if (r < 0 || r >= HH) continue;
        for (int chunk = 0; chunk < 8; ++chunk) {
            const int ci0 = chunk * 32;
            __syncthreads();
#pragma unroll
            for (int i = 0; i < 8; ++i) {
                int flat = t + 256 * i;
                int ci = flat >> 6;
                int w = flat & 63;
                xsf[ci][1 + w] = x[xbase + (size_t)(ci0 + ci) * 4096 + r * 64 + w];
            }
            if (t < 32) {
                xsf[t][0] = 0.f;
                xsf[t][65] = 0.f;
                xsf[t][66] = 0.f;
                xsf[t][67] = 0.f;
            }
#pragma unroll
            for (int j = 0; j < 24; ++j) {
                int e = t + 256 * j;
                int co = e / 96;
                int rem = e - co * 96;
                int ci = rem / 3;
                int kw = rem - ci * 3;
                size_t g = (((size_t)(co0 + co) * 256 + (ci0 + ci)) * 3 + kh) * 3 + kw;
                float v = a0 * wt[g] + a1 * wt[g + NBANK_STRIDE] +
                          a2 * wt[g + 2 * NBANK_STRIDE] + a3 * wt[g + 3 * NBANK_STRIDE];
                wshf[kw][ci][co] = v;
            }
            __syncthreads();
            for (int ci = 0; ci < 32; ++ci) {
                float4 w0 = *(const float4*)&wshf[0][ci][tx * 4];
                float4 w1v = *(const float4*)&wshf[1][ci][tx * 4];
                float4 w2v = *(const float4*)&wshf[2][ci][tx * 4];
                float4 xa = *(const float4*)&xsf[ci][ty * 4];
                float4 xb = *(const float4*)&xsf[ci][ty * 4 + 4];
                float v[8] = {xa.x, xa.y, xa.z, xa.w, xb.x, xb.y, xb.z, xb.w};
                float aw[3][4] = {{w0.x, w0.y, w0.z, w0.w},
                                  {w1v.x, w1v.y, w1v.z, w1v.w},
                                  {w2v.x, w2v.y, w2v.z, w2v.w}};
#pragma unroll
                for (int kw = 0; kw < 3; ++kw)
#pragma unroll
                    for (int i = 0; i < 4; ++i)
#pragma unroll
                        for (int j = 0; j < 4; ++j)
                            acc[i][j] += aw[kw][i] * v[j + kw];
            }
        }
    }
    size_t obase = (((size_t)b * COUT + co0 + tx * 4) * 64 + h) * 64 + ty * 4;
#pragma unroll
    for (int i = 0; i < 4; ++i) {
        float4 o = {acc[i][0], acc[i][1], acc[i][2], acc[i][3]};
        *(float4*)&out[obase + (size_t)i * 4096] = o;
    }
}

__global__ __launch_bounds__(256) void bn_stats_kernel(const float* __restrict__ out,
                                                       const float* __restrict__ gamma,
                                                       const float* __restrict__ beta,
                                                       float* __restrict__ scale,
                                                       float* __restrict__ shift) {
    const int co = blockIdx.x;
    const int t = threadIdx.x;
    float s = 0.f, sq = 0.f;
    for (int b = 0; b < BB; ++b) {
        const float4* p = (const float4*)(out + ((size_t)b * 256 + co) * 4096);
#pragma unroll
        for (int i = 0; i < 4; ++i) {
            float4 v = p[t + 256 * i];
            s += v.x + v.y + v.z + v.w;
            sq += v.x * v.x + v.y * v.y + v.z * v.z + v.w * v.w;
        }
    }
#pragma unroll
    for (int off = 32; off > 0; off >>= 1) {
        s += __shfl_down(s, off, 64);
        sq += __shfl_down(sq, off, 64);
    }
    __shared__ float rs[4], rq[4];
    if ((t & 63) == 0) {
        rs[t >> 6] = s;
        rq[t >> 6] = sq;
    }
    __syncthreads();
    if (t == 0) {
        float S = rs[0] + rs[1] + rs[2] + rs[3];
        float Q = rq[0] + rq[1] + rq[2] + rq[3];
        float mean = S * (1.f / 65536.f);
        float var = Q * (1.f / 65536.f) - mean * mean;
        float inv = rsqrtf(var + 1e-5f);
        float sc = gamma[co] * inv;
        scale[co] = sc;
        shift[co] = beta[co] - mean * sc;
    }
}

__global__ __launch_bounds__(256) void bn_apply_kernel(float* __restrict__ out,
                                                       const float* __restrict__ scale,
                                                       const float* __restrict__ shift) {
    const int gid = blockIdx.x * 256 + threadIdx.x;
    const int c = (gid >> 10) & 255;
    float4* p = (float4*)out;
    float4 v = p[gid];
    const float sc = scale[c], sh = shift[c];
    v.x = v.x * sc + sh;
    v.y = v.y * sc + sh;
    v.z = v.z * sc + sh;
    v.w = v.w * sc + sh;
    p[gid] = v;
}

extern "C" void kernel_launch(void* const* d_in, const int* in_sizes, int n_in,
                              void* d_out, int out_size, void* d_ws, size_t ws_size,
                              hipStream_t stream) {
    (void)in_sizes; (void)n_in; (void)out_size;
    const float* x = (const float*)d_in[0];
    const float* wt = (const float*)d_in[1];
    const float* gamma = (const float*)d_in[2];
    const float* beta = (const float*)d_in[3];
    AttnParams ap;
    for (int n = 0; n < 4; ++n) {
        ap.w1[n] = (const float*)d_in[4 + 3 * n];
        ap.w2[n] = (const float*)d_in[5 + 3 * n];
        ap.b2[n] = (const float*)d_in[6 + 3 * n];
    }
    float* ws = (float*)d_ws;
    float* pooled = ws;
    float* alpha = ws + 4096;
    float* scale = ws + 4160;
    float* shift = ws + 4416;
    float* out = (float*)d_out;

    gap_kernel<<<4096, 256, 0, stream>>>(x, pooled);
    attn_kernel<<<16, 64, 0, stream>>>(pooled, ap, alpha);

    if (ws_size >= WS_NEED) {
        unsigned short* xT = (unsigned short*)((char*)d_ws + WS_XT_OFF);
        unsigned short* dynwT = (unsigned short*)((char*)d_ws + WS_DW_OFF);
        xpose_kernel<<<dim3(8, 64, 16), 256, 0, stream>>>(x, xT);
        dynw_kernel<<<256, 256, 0, stream>>>(wt, alpha, dynwT);
        conv_mfma_kernel<<<dim3(32, 2, 16), 256, 0, stream>>>(xT, dynwT, out);
    } else {
        conv_fp32_kernel<<<dim3(64, 4, 16), 256, 0, stream>>>(x, wt, alpha, out);
    }

    bn_stats_kernel<<<256, 256, 0, stream>>>(out, gamma, beta, scale, shift);
    bn_apply_kernel<<<16384, 256, 0, stream>>>(out, scale, shift);
}

// Round 3
// 277.819 us; speedup vs baseline: 6.7407x; 1.2079x over previous
//
#include <hip/hip_runtime.h>
#include <math.h>

#define BB 16
#define CIN 256
#define COUT 256
#define HH 64
#define WW 64
#define NBANK_STRIDE 589824  // 256*256*9

typedef short bf16x8 __attribute__((ext_vector_type(8)));
typedef float f32x4 __attribute__((ext_vector_type(4)));

// ws layout (bytes), total exactly 52461568 (same as round 2):
// [0,16384)      pooled[16][256] f32 (zero->xpose atomics->attn). attn writes
//                alpha[b] into pooled[b][0..3]. After conv: reused as
//                scale[256] @0, shift[256] @1024.
// [16384,32768)  bn_part[2][256][8] f32 (zeroed by attn, atomics by conv)
// [32768,+33554432)   xT  [16][4096 pix][256 ci] bf16 (NHWC)
// [33587200,+18874368) dynwT [16][9][256 co][256 ci] bf16
#define WS_XT_OFF 32768
#define WS_DW_OFF 33587200
#define WS_NEED   52461568ULL

static __device__ __forceinline__ short f2bf(float f) {
    union { float f; unsigned u; } v; v.f = f;
    unsigned r = v.u + 0x7FFF + ((v.u >> 16) & 1);
    return (short)(r >> 16);
}

struct AttnParams {
    const float* w1[4];
    const float* w2[4];
    const float* b2[4];
};

__global__ __launch_bounds__(256) void zero_kernel(float* __restrict__ ws) {
    ws[blockIdx.x * 256 + threadIdx.x] = 0.f;  // pooled [0,16384)
}

// x [b][ci][h][w] f32 -> xT [b][h*64+w][ci] bf16 ; also accumulates GAP sums.
__global__ __launch_bounds__(256) void xpose_kernel(const float* __restrict__ x,
                                                    short* __restrict__ xT,
                                                    float* __restrict__ pooled) {
    const int ci0 = blockIdx.x * 32;
    const int h = blockIdx.y;
    const int b = blockIdx.z;
    const int t = threadIdx.x;
    __shared__ __align__(16) short tile[64][40];  // [w][ci]
    {
        const int ci = t >> 3;    // 0..31
        const int l = t & 7;      // 0..7
        const float4* src = (const float4*)(x + ((size_t)(b * 256 + ci0 + ci)) * 4096 + h * 64);
        float4 v1 = src[l * 2];
        float4 v2 = src[l * 2 + 1];
        tile[l * 8 + 0][ci] = f2bf(v1.x);
        tile[l * 8 + 1][ci] = f2bf(v1.y);
        tile[l * 8 + 2][ci] = f2bf(v1.z);
        tile[l * 8 + 3][ci] = f2bf(v1.w);
        tile[l * 8 + 4][ci] = f2bf(v2.x);
        tile[l * 8 + 5][ci] = f2bf(v2.y);
        tile[l * 8 + 6][ci] = f2bf(v2.z);
        tile[l * 8 + 7][ci] = f2bf(v2.w);
        // GAP partial: sum this thread's 8 values, reduce over l (lanes xor 1,2,4)
        float s = v1.x + v1.y + v1.z + v1.w + v2.x + v2.y + v2.z + v2.w;
        s += __shfl_xor(s, 1, 64);
        s += __shfl_xor(s, 2, 64);
        s += __shfl_xor(s, 4, 64);
        if (l == 0) atomicAdd(&pooled[b * 256 + ci0 + ci], s);
    }
    __syncthreads();
    {
        const int w = t >> 2;    // 0..63
        const int s = t & 3;     // 0..3
        bf16x8 val = *(const bf16x8*)&tile[w][s * 8];
        *(bf16x8*)&xT[((size_t)b * 4096 + h * 64 + w) * 256 + ci0 + s * 8] = val;
    }
}

// 4 waves, one branch per wave. Writes alpha[b] into pooled[b][0..3].
// Also zeroes bn_part (ws floats [4096,8192)).
__global__ __launch_bounds__(256) void attn_kernel(AttnParams p, float* __restrict__ ws_f) {
    const int b = blockIdx.x;
    const int t = threadIdx.x;
    const int wv = t >> 6;
    const int lane = t & 63;
    __shared__ float ps[256];
    __shared__ float hs[4][64];
    __shared__ float lg[4][4];
    __shared__ float sm[4][4];
    ws_f[4096 + b * 256 + t] = 0.f;  // zero bn_part slice
    ps[t] = ws_f[b * 256 + t] * (1.0f / 4096.0f);
    __syncthreads();
    {
        const float4* w1v = (const float4*)(p.w1[wv] + lane * 256);
        float h = 0.f;
#pragma unroll 8
        for (int i = 0; i < 64; ++i) {
            float4 w4 = w1v[i];
            h += w4.x * ps[i * 4 + 0] + w4.y * ps[i * 4 + 1] +
                 w4.z * ps[i * 4 + 2] + w4.w * ps[i * 4 + 3];
        }
        hs[wv][lane] = fmaxf(h, 0.f);
    }
    __syncthreads();
    if (t < 16) {
        const int n = t >> 2, j = t & 3;
        const float* w2 = p.w2[n];
        float l = p.b2[n][j];
        for (int m = 0; m < 64; ++m) l += w2[j * 64 + m] * hs[n][m];
        lg[n][j] = l;
    }
    __syncthreads();
    if (t < 4) {
        const int n = t;
        float mx = fmaxf(fmaxf(lg[n][0], lg[n][1]), fmaxf(lg[n][2], lg[n][3]));
        float e0 = expf(lg[n][0] - mx), e1 = expf(lg[n][1] - mx);
        float e2 = expf(lg[n][2] - mx), e3 = expf(lg[n][3] - mx);
        float inv = 1.f / (e0 + e1 + e2 + e3);
        sm[n][0] = e0 * inv; sm[n][1] = e1 * inv; sm[n][2] = e2 * inv; sm[n][3] = e3 * inv;
    }
    __syncthreads();
    if (t < 4) ws_f[b * 256 + t] = sm[0][t] * sm[1][t] * sm[2][t] * sm[3][t];
}

// dynwT[b][khw][co][ci] = sum_n alpha[b][n] * wt[n][co][ci][kh][kw], bf16.
__global__ __launch_bounds__(256) void dynw_kernel(const float* __restrict__ wt,
                                                   const float* __restrict__ ws_f,
                                                   short* __restrict__ dynwT) {
    const int co = blockIdx.x;
    const int ci = threadIdx.x;
    float w[4][9];
#pragma unroll
    for (int n = 0; n < 4; ++n) {
        const size_t base = ((size_t)(n * 256 + co) * 256 + ci) * 9;
#pragma unroll
        for (int k = 0; k < 9; ++k) w[n][k] = wt[base + k];
    }
    for (int b = 0; b < BB; ++b) {
        const float a0 = ws_f[b * 256 + 0];
        const float a1 = ws_f[b * 256 + 1];
        const float a2 = ws_f[b * 256 + 2];
        const float a3 = ws_f[b * 256 + 3];
#pragma unroll
        for (int k = 0; k < 9; ++k) {
            float v = a0 * w[0][k] + a1 * w[1][k] + a2 * w[2][k] + a3 * w[3][k];
            dynwT[((size_t)(b * 9 + k) * 256 + co) * 256 + ci] = f2bf(v);
        }
    }
}

// Implicit-GEMM conv, MFMA 16x16x32 bf16.
// Block: 128 co x 256 pixels (4 rows). 4 waves: wy = co half (64), wx = pixel
// half (128 pix = 2 rows). A (weights) double-buffered in LDS, prefetched from
// global during compute; 1 barrier per khw. BN partial sums in epilogue.
__global__ __launch_bounds__(256, 2) void conv_mfma_kernel(const short* __restrict__ xT,
                                                           const short* __restrict__ dynwT,
                                                           float* __restrict__ out,
                                                           float* __restrict__ bn_part) {
    const int nt = blockIdx.x;    // 0..15 -> rows r0..r0+3
    const int mt = blockIdx.y;    // 0..1
    const int b = blockIdx.z;
    const int t = threadIdx.x;
    const int lane = t & 63;
    const int wv = t >> 6;
    const int wx = wv & 1;        // pixel half
    const int wy = wv >> 1;       // co half
    const int mh = lane & 15;
    const int q = lane >> 4;
    const int r0 = nt * 4;
    const int co0 = mt * 128;

    __shared__ __align__(16) short xs[396 * 40];     // [p=lr*66+lc][ci], pad 32->40
    __shared__ __align__(16) short As[2][128 * 40];  // dbuf [co][ci]
    __shared__ float red[128][2][2];                 // [co_l][stat][wx]

    f32x4 acc[4][8];
#pragma unroll
    for (int i = 0; i < 4; ++i)
#pragma unroll
        for (int j = 0; j < 8; ++j) acc[i][j] = (f32x4){0.f, 0.f, 0.f, 0.f};

    // A staging: 512 elems (128 rows x 4 subs), 2 per thread
    const int arow0 = t >> 2;          // 0..63
    const int asub = t & 3;
    const short* Ab = dynwT + (size_t)b * 9 * 65536 + (co0 + arow0) * 256 + asub * 8;
    const int a_lds0 = arow0 * 40 + asub * 8;
    const int a_lds1 = (arow0 + 64) * 40 + asub * 8;
    const int a_rd = (wy * 64 + mh) * 40 + q * 8;    // + mi*640

    const bf16x8 zero8 = {0, 0, 0, 0, 0, 0, 0, 0};

    for (int cc = 0; cc < 8; ++cc) {
        const int ci0 = cc * 32;
        __syncthreads();
        // prefetch A for khw=0 (latency overlapped with xs staging)
        bf16x8 pa0 = *(const bf16x8*)(Ab + ci0);
        bf16x8 pa1 = *(const bf16x8*)(Ab + 64 * 256 + ci0);
        // stage xs: 396 pixels x 32 ci (zero-padded halo)
#pragma unroll
        for (int i = 0; i < 7; ++i) {
            int idx = t + 256 * i;
            if (idx < 1584) {
                int p = idx >> 2;
                int sub = idx & 3;
                int lr = p / 66;
                int lc = p - lr * 66;
                int r = r0 - 1 + lr;
                int c = lc - 1;
                bf16x8 v = zero8;
                if ((unsigned)r < 64u && (unsigned)c < 64u)
                    v = *(const bf16x8*)&xT[((size_t)b * 4096 + r * 64 + c) * 256 + ci0 + sub * 8];
                *(bf16x8*)&xs[p * 40 + sub * 8] = v;
            }
        }
        *(bf16x8*)&As[0][a_lds0] = pa0;
        *(bf16x8*)&As[0][a_lds1] = pa1;
        __syncthreads();
#pragma unroll
        for (int khw = 0; khw < 9; ++khw) {
            const int kh = khw / 3;
            const int kw = khw - kh * 3;
            bf16x8 na0, na1;
            if (khw < 8) {
                na0 = *(const bf16x8*)(Ab + (khw + 1) * 65536 + ci0);
                na1 = *(const bf16x8*)(Ab + (khw + 1) * 65536 + 64 * 256 + ci0);
            }
            bf16x8 bfr[8];
#pragma unroll
            for (int ni = 0; ni < 8; ++ni) {
                const int row_l = wx * 2 + (ni >> 2) + kh;
                const int col_l = (ni & 3) * 16 + kw + mh;
                bfr[ni] = *(const bf16x8*)&xs[(row_l * 66 + col_l) * 40 + q * 8];
            }
#pragma unroll
            for (int mi = 0; mi < 4; ++mi) {
                bf16x8 af = *(const bf16x8*)&As[khw & 1][a_rd + mi * 640];
#pragma unroll
                for (int ni = 0; ni < 8; ++ni)
                    acc[mi][ni] = __builtin_amdgcn_mfma_f32_16x16x32_bf16(af, bfr[ni], acc[mi][ni], 0, 0, 0);
            }
            if (khw < 8) {
                *(bf16x8*)&As[(khw + 1) & 1][a_lds0] = na0;
                *(bf16x8*)&As[(khw + 1) & 1][a_lds1] = na1;
            }
            __syncthreads();
        }
    }

    // epilogue: store + BN partials. D: col(pixel)=mh, row(co)=q*4+reg.
    float s16[4][4], q16[4][4];
#pragma unroll
    for (int mi = 0; mi < 4; ++mi)
#pragma unroll
        for (int reg = 0; reg < 4; ++reg) { s16[mi][reg] = 0.f; q16[mi][reg] = 0.f; }

#pragma unroll
    for (int mi = 0; mi < 4; ++mi) {
#pragma unroll
        for (int ni = 0; ni < 8; ++ni) {
            const int pix = wx * 128 + ni * 16 + mh;
            const int h = r0 + (pix >> 6);
            const int w = pix & 63;
#pragma unroll
            for (int reg = 0; reg < 4; ++reg) {
                const int co = co0 + wy * 64 + mi * 16 + q * 4 + reg;
                const float e = acc[mi][ni][reg];
                out[(((size_t)b * 256 + co) << 12) + (h << 6) + w] = e;
                s16[mi][reg] += e;
                q16[mi][reg] += e * e;
            }
        }
    }
#pragma unroll
    for (int mi = 0; mi < 4; ++mi)
#pragma unroll
        for (int reg = 0; reg < 4; ++reg) {
            float s = s16[mi][reg], sq = q16[mi][reg];
            s += __shfl_xor(s, 1, 64);  sq += __shfl_xor(sq, 1, 64);
            s += __shfl_xor(s, 2, 64);  sq += __shfl_xor(sq, 2, 64);
            s += __shfl_xor(s, 4, 64);  sq += __shfl_xor(sq, 4, 64);
            s += __shfl_xor(s, 8, 64);  sq += __shfl_xor(sq, 8, 64);
            if (mh == 0) {
                const int co_l = wy * 64 + mi * 16 + q * 4 + reg;
                red[co_l][0][wx] = s;
                red[co_l][1][wx] = sq;
            }
        }
    __syncthreads();
    {
        const int co_l = t >> 1;
        const int st = t & 1;
        float v = red[co_l][st][0] + red[co_l][st][1];
        atomicAdd(&bn_part[(st * 256 + co0 + co_l) * 8 + (nt & 7)], v);
    }
}

__global__ __launch_bounds__(256) void bn_finalize_kernel(const float* __restrict__ bn_part,
                                                          const float* __restrict__ gamma,
                                                          const float* __restrict__ beta,
                                                          float* __restrict__ scale,
                                                          float* __restrict__ shift) {
    const int co = threadIdx.x;
    float S = 0.f, Q = 0.f;
#pragma unroll
    for (int s = 0; s < 8; ++s) {
        S += bn_part[(co) * 8 + s];
        Q += bn_part[(256 + co) * 8 + s];
    }
    const float mean = S * (1.f / 65536.f);
    const float var = Q * (1.f / 65536.f) - mean * mean;
    const float inv = rsqrtf(var + 1e-5f);
    const float sc = gamma[co] * inv;
    scale[co] = sc;
    shift[co] = beta[co] - mean * sc;
}

__global__ __launch_bounds__(256) void bn_apply_kernel(float* __restrict__ out,
                                                       const float* __restrict__ scale,
                                                       const float* __restrict__ shift) {
    const int gid = blockIdx.x * 256 + threadIdx.x;
    const int c = (gid >> 10) & 255;
    float4* p = (float4*)out;
    float4 v = p[gid];
    const float sc = scale[c], sh = shift[c];
    v.x = v.x * sc + sh;
    v.y = v.y * sc + sh;
    v.z = v.z * sc + sh;
    v.w = v.w * sc + sh;
    p[gid] = v;
}

// ---------------- fallback path (ws too small) ----------------
__global__ __launch_bounds__(256) void gap_kernel(const float* __restrict__ x,
                                                  float* __restrict__ pooled) {
    const int plane = blockIdx.x;
    const float4* p = (const float4*)(x + (size_t)plane * 4096);
    const int t = threadIdx.x;
    float s = 0.f;
#pragma unroll
    for (int i = 0; i < 4; ++i) {
        float4 v = p[t + 256 * i];
        s += v.x + v.y + v.z + v.w;
    }
#pragma unroll
    for (int off = 32; off > 0; off >>= 1) s += __shfl_down(s, off, 64);
    __shared__ float red[4];
    if ((t & 63) == 0) red[t >> 6] = s;
    __syncthreads();
    if (t == 0) pooled[plane] = (red[0] + red[1] + red[2] + red[3]) * (1.0f / 4096.0f);
}

__global__ __launch_bounds__(64) void attn64_kernel(const float* __restrict__ pooled,
                                                    AttnParams p,
                                                    float* __restrict__ alpha) {
    const int b = blockIdx.x;
    const int t = threadIdx.x;
    __shared__ float ps[256];
    __shared__ float hs[64];
    __shared__ float lg[4];
    __shared__ float prod[4];
#pragma unroll
    for (int i = 0; i < 4; ++i) ps[t + 64 * i] = pooled[b * 256 + t + 64 * i];
    if (t < 4) prod[t] = 1.f;
    __syncthreads();
    for (int n = 0; n < 4; ++n) {
        const float* w1 = p.w1[n];
        float h = 0.f;
        for (int c = 0; c < 256; ++c) h += w1[t * 256 + c] * ps[c];
        hs[t] = fmaxf(h, 0.f);
        __syncthreads();
        if (t < 4) {
            const float* w2 = p.w2[n];
            float l = p.b2[n][t];
            for (int m = 0; m < 64; ++m) l += w2[t * 64 + m] * hs[m];
            lg[t] = l;
        }
        __syncthreads();
        if (t == 0) {
            float mx = fmaxf(fmaxf(lg[0], lg[1]), fmaxf(lg[2], lg[3]));
            float e0 = expf(lg[0] - mx), e1 = expf(lg[1] - mx);
            float e2 = expf(lg[2] - mx), e3 = expf(lg[3] - mx);
            float inv = 1.f / (e0 + e1 + e2 + e3);
            prod[0] *= e0 * inv; prod[1] *= e1 * inv;
            prod[2] *= e2 * inv; prod[3] *= e3 * inv;
        }
        __syncthreads();
    }
    if (t < 4) alpha[b * 4 + t] = prod[t];
}

__global__ __launch_bounds__(256) void conv_fp32_kernel(const float* __restrict__ x,
                                                        const float* __restrict__ wt,
                                                        const float* __restrict__ alpha,
                                                        float* __restrict__ out) {
    const int h = blockIdx.x;
    const int cot = blockIdx.y;
    const int b = blockIdx.z;
    const int t = threadIdx.x;
    const int tx = t & 15;
    const int ty = t >> 4;
    const int co0 = cot * 64;
    __shared__ __align__(16) float xsf[32][68];
    __shared__ __align__(16) float wshf[3][32][68];
    const float a0 = alpha[b * 4 + 0], a1 = alpha[b * 4 + 1];
    const float a2 = alpha[b * 4 + 2], a3 = alpha[b * 4 + 3];
    float acc[4][4];
#pragma unroll
    for (int i = 0; i < 4; ++i)
#pragma unroll
        for (int j = 0; j < 4; ++j) acc[i][j] = 0.f;
    const size_t xbase = (size_t)b * CIN * 4096;
    for (int kh = 0; kh < 3; ++kh) {
        const int r = h + kh - 1;
        if (r < 0 || r >= HH) continue;
        for (int chunk = 0; chunk < 8; ++chunk) {
            const int ci0 = chunk * 32;
            __syncthreads();
#pragma unroll
            for (int i = 0; i < 8; ++i) {
                int flat = t + 256 * i;
                int ci = flat >> 6;
                int w = flat & 63;
                xsf[ci][1 + w] = x[xbase + (size_t)(ci0 + ci) * 4096 + r * 64 + w];
            }
            if (t < 32) { xsf[t][0] = 0.f; xsf[t][65] = 0.f; xsf[t][66] = 0.f; xsf[t][67] = 0.f; }
#pragma unroll
            for (int j = 0; j < 24; ++j) {
                int e = t + 256 * j;
                int co = e / 96;
                int rem = e - co * 96;
                int ci = rem / 3;
                int kw = rem - ci * 3;
                size_t g = (((size_t)(co0 + co) * 256 + (ci0 + ci)) * 3 + kh) * 3 + kw;
                wshf[kw][ci][co] = a0 * wt[g] + a1 * wt[g + NBANK_STRIDE] +
                                   a2 * wt[g + 2 * NBANK_STRIDE] + a3 * wt[g + 3 * NBANK_STRIDE];
            }
            __syncthreads();
            for (int ci = 0; ci < 32; ++ci) {
                float4 w0 = *(const float4*)&wshf[0][ci][tx * 4];
                float4 w1v = *(const float4*)&wshf[1][ci][tx * 4];
                float4 w2v = *(const float4*)&wshf[2][ci][tx * 4];
                float4 xa = *(const float4*)&xsf[ci][ty * 4];
                float4 xb = *(const float4*)&xsf[ci][ty * 4 + 4];
                float v[8] = {xa.x, xa.y, xa.z, xa.w, xb.x, xb.y, xb.z, xb.w};
                float aw[3][4] = {{w0.x, w0.y, w0.z, w0.w},
                                  {w1v.x, w1v.y, w1v.z, w1v.w},
                                  {w2v.x, w2v.y, w2v.z, w2v.w}};
#pragma unroll
                for (int kw = 0; kw < 3; ++kw)
#pragma unroll
                    for (int i = 0; i < 4; ++i)
#pragma unroll
                        for (int j = 0; j < 4; ++j)
                            acc[i][j] += aw[kw][i] * v[j + kw];
            }
        }
    }
    size_t obase = (((size_t)b * COUT + co0 + tx * 4) * 64 + h) * 64 + ty * 4;
#pragma unroll
    for (int i = 0; i < 4; ++i) {
        float4 o = {acc[i][0], acc[i][1], acc[i][2], acc[i][3]};
        *(float4*)&out[obase + (size_t)i * 4096] = o;
    }
}

__global__ __launch_bounds__(256) void bn_stats_kernel(const float* __restrict__ out,
                                                       const float* __restrict__ gamma,
                                                       const float* __restrict__ beta,
                                                       float* __restrict__ scale,
                                                       float* __restrict__ shift) {
    const int co = blockIdx.x;
    const int t = threadIdx.x;
    float s = 0.f, sq = 0.f;
    for (int b = 0; b < BB; ++b) {
        const float4* p = (const float4*)(out + ((size_t)b * 256 + co) * 4096);
#pragma unroll
        for (int i = 0; i < 4; ++i) {
            float4 v = p[t + 256 * i];
            s += v.x + v.y + v.z + v.w;
            sq += v.x * v.x + v.y * v.y + v.z * v.z + v.w * v.w;
        }
    }
#pragma unroll
    for (int off = 32; off > 0; off >>= 1) {
        s += __shfl_down(s, off, 64);
        sq += __shfl_down(sq, off, 64);
    }
    __shared__ float rs[4], rq[4];
    if ((t & 63) == 0) { rs[t >> 6] = s; rq[t >> 6] = sq; }
    __syncthreads();
    if (t == 0) {
        float S = rs[0] + rs[1] + rs[2] + rs[3];
        float Q = rq[0] + rq[1] + rq[2] + rq[3];
        float mean = S * (1.f / 65536.f);
        float var = Q * (1.f / 65536.f) - mean * mean;
        float inv = rsqrtf(var + 1e-5f);
        float sc = gamma[co] * inv;
        scale[co] = sc;
        shift[co] = beta[co] - mean * sc;
    }
}

extern "C" void kernel_launch(void* const* d_in, const int* in_sizes, int n_in,
                              void* d_out, int out_size, void* d_ws, size_t ws_size,
                              hipStream_t stream) {
    (void)in_sizes; (void)n_in; (void)out_size;
    const float* x = (const float*)d_in[0];
    const float* wt = (const float*)d_in[1];
    const float* gamma = (const float*)d_in[2];
    const float* beta = (const float*)d_in[3];
    AttnParams ap;
    for (int n = 0; n < 4; ++n) {
        ap.w1[n] = (const float*)d_in[4 + 3 * n];
        ap.w2[n] = (const float*)d_in[5 + 3 * n];
        ap.b2[n] = (const float*)d_in[6 + 3 * n];
    }
    float* ws_f = (float*)d_ws;
    float* out = (float*)d_out;

    if (ws_size >= WS_NEED) {
        short* xT = (short*)((char*)d_ws + WS_XT_OFF);
        short* dynwT = (short*)((char*)d_ws + WS_DW_OFF);
        float* bn_part = ws_f + 4096;
        float* scale = ws_f;         // reuses dead pooled space
        float* shift = ws_f + 256;

        zero_kernel<<<16, 256, 0, stream>>>(ws_f);
        xpose_kernel<<<dim3(8, 64, 16), 256, 0, stream>>>(x, xT, ws_f);
        attn_kernel<<<16, 256, 0, stream>>>(ap, ws_f);
        dynw_kernel<<<256, 256, 0, stream>>>(wt, ws_f, dynwT);
        conv_mfma_kernel<<<dim3(16, 2, 16), 256, 0, stream>>>(xT, dynwT, out, bn_part);
        bn_finalize_kernel<<<1, 256, 0, stream>>>(bn_part, gamma, beta, scale, shift);
        bn_apply_kernel<<<16384, 256, 0, stream>>>(out, scale, shift);
    } else {
        float* pooled = ws_f;
        float* alpha = ws_f + 4096;
        float* scale = ws_f + 4160;
        float* shift = ws_f + 4416;
        gap_kernel<<<4096, 256, 0, stream>>>(x, pooled);
        attn64_kernel<<<16, 64, 0, stream>>>(pooled, ap, alpha);
        conv_fp32_kernel<<<dim3(64, 4, 16), 256, 0, stream>>>(x, wt, alpha, out);
        bn_stats_kernel<<<256, 256, 0, stream>>>(out, gamma, beta, scale, shift);
        bn_apply_kernel<<<16384, 256, 0, stream>>>(out, scale, shift);
    }
}